// Round 1
// baseline (182.699 us; speedup 1.0000x reference)
//
#include <hip/hip_runtime.h>
#include <hip/hip_bf16.h>
#include <stdint.h>

// Problem constants (from reference setup_inputs)
#define MB 256
#define LW 200      // words per batch
#define NS 5        // senses per word
#define DD 128      // embedding dim
#define VV 50000    // vocab
#define OO 50000    // output vocab
#define LSTOK 1000  // LW*NS

#define NSTRIPES 782  // ceil(50000/64)

typedef __attribute__((ext_vector_type(8))) short bf16x8;
typedef __attribute__((ext_vector_type(4))) float f32x4;
typedef __attribute__((ext_vector_type(8))) unsigned short u16x8;

__device__ inline unsigned short f2bf(float f){
  unsigned u = __float_as_uint(f);
  unsigned r = (u + 0x7fffu + ((u >> 16) & 1u)) >> 16;  // RNE
  return (unsigned short)r;
}
__device__ inline float bf2f(unsigned short h){
  return __uint_as_float(((unsigned)h) << 16);
}
__device__ inline float wsum64(float v){
  #pragma unroll
  for (int o = 1; o < 64; o <<= 1) v += __shfl_xor(v, o, 64);
  return v;
}
__device__ inline float wmax64(float v){
  #pragma unroll
  for (int o = 1; o < 64; o <<= 1) v = fmaxf(v, __shfl_xor(v, o, 64));
  return v;
}

// ---------------------------------------------------------------------------
// Sniff whether inputs are int64 (odd dwords == high words == 0) or int32.
// Writes flag=1 for int64 (index stride 2 dwords), 0 for int32.
__global__ void k_sniff(const unsigned* __restrict__ p, int* __restrict__ flag){
  unsigned v = p[2*threadIdx.x + 1];
  unsigned long long b = __ballot(v != 0u);
  if (threadIdx.x == 0) *flag = (b == 0ull) ? 1 : 0;
}

// ---------------------------------------------------------------------------
// W (128 x 50000 f32, row-major) -> Wt (50000 x 128 bf16, row-major)
__global__ __launch_bounds__(256) void k_prepw(const float* __restrict__ W,
                                               unsigned short* __restrict__ Wt){
  __shared__ float tile[64][129];
  long long n0 = (long long)blockIdx.x * 64;
  int t = threadIdx.x;
  int j = t & 63, kk = t >> 6;
  #pragma unroll
  for (int k = kk; k < 128; k += 4){
    float v = 0.f;
    if (n0 + j < OO) v = W[(long long)k*OO + n0 + j];
    tile[j][k] = v;
  }
  __syncthreads();
  #pragma unroll
  for (int c = t; c < 4096; c += 256){
    int row = c >> 6, dw = c & 63;
    if (n0 + row < OO){
      unsigned pr = (unsigned)f2bf(tile[row][2*dw]) |
                    ((unsigned)f2bf(tile[row][2*dw+1]) << 16);
      ((unsigned*)Wt)[(n0 + row)*64 + dw] = pr;
    }
  }
}

// ---------------------------------------------------------------------------
// Attention pipeline: one block per batch, 512 threads (8 waves).
__global__ __launch_bounds__(512) void k_attn(
    const int* __restrict__ in32, const int* __restrict__ flagp,
    const float* __restrict__ lwp, const unsigned char* __restrict__ maskp,
    const float* __restrict__ emb, const float* __restrict__ w_attn,
    const float* __restrict__ b_attn_p,
    unsigned short* __restrict__ hiddenB)
{
  __shared__ float wm[LW*DD];    // word_mean, 200*128 f32 = 100 KB
  __shared__ float imp[LW];
  __shared__ float ww[LW];
  __shared__ float gm[DD];
  __shared__ float cx[DD];
  __shared__ float red[16*DD];   // reduction scratch (8 KB)

  int b = blockIdx.x;
  int t = threadIdx.x;
  int f = *flagp;                      // 1 -> int64 inputs, 0 -> int32
  float lw = lwp[b];
  float b_attn = *b_attn_p;
  long long base = (long long)b * LSTOK;

  // ---- Pass 1: gmean = sum over 1000 rows * lw / 5
  {
    int q = t & 31, r = t >> 5;        // q: float4 slot, r: 16 row groups
    float4 acc = {0.f,0.f,0.f,0.f};
    for (int i = r; i < LSTOK; i += 16){
      int idx = in32[(base + i) << f];
      float4 v = *(const float4*)(emb + (long long)idx*DD + q*4);
      acc.x += v.x; acc.y += v.y; acc.z += v.z; acc.w += v.w;
    }
    *(float4*)&red[r*DD + q*4] = acc;
  }
  __syncthreads();
  if (t < DD){
    float s = 0.f;
    #pragma unroll
    for (int r = 0; r < 16; r++) s += red[r*DD + t];
    gm[t] = s * lw * 0.2f;
  }
  __syncthreads();

  int wv = t >> 6, l = t & 63;
  float2 g2  = *(float2*)&gm[2*l];
  float2 wa2 = *(const float2*)(w_attn + 2*l);

  // ---- Pass 2: per-word sense softmax -> word_mean, word_imp
  for (int wrd = wv; wrd < LW; wrd += 8){
    long long p0 = base + (long long)wrd * NS;
    float2 e[NS]; int ids[NS]; float si[NS];
    #pragma unroll
    for (int s = 0; s < NS; s++){
      int id = in32[(p0 + s) << f];
      ids[s] = id;
      float2 ev = *(const float2*)(emb + (long long)id*DD + 2*l);
      e[s] = ev;
      si[s] = ev.x*g2.x + ev.y*g2.y;
    }
    #pragma unroll
    for (int s = 0; s < NS; s++) si[s] = wsum64(si[s]);
    float mx = fmaxf(fmaxf(fmaxf(si[0],si[1]), fmaxf(si[2],si[3])), si[4]);
    float sw[NS]; float ssum = 0.f;
    #pragma unroll
    for (int s = 0; s < NS; s++){ sw[s] = __expf(si[s]-mx); ssum += sw[s]; }
    float inv = 1.0f / ssum;
    float2 m2 = {0.f, 0.f};
    #pragma unroll
    for (int s = 0; s < NS; s++){
      float w = sw[s]*inv;
      m2.x += w*e[s].x; m2.y += w*e[s].y;
    }
    *(float2*)&wm[wrd*DD + 2*l] = m2;
    float wi = wsum64(m2.x*wa2.x + m2.y*wa2.y) + b_attn;
    if (maskp[(long long)b*LW + wrd]) wi = -INFINITY;
    if (l == 0) imp[wrd] = wi;
  }
  __syncthreads();

  // ---- word softmax over 200 (wave 0)
  if (wv == 0){
    float v[4]; float mx = -INFINITY;
    #pragma unroll
    for (int j = 0; j < 4; j++){
      int i = l + 64*j;
      v[j] = (i < LW) ? imp[i] : -INFINITY;
      mx = fmaxf(mx, v[j]);
    }
    mx = wmax64(mx);
    float s = 0.f;
    #pragma unroll
    for (int j = 0; j < 4; j++){
      int i = l + 64*j;
      if (i < LW){ v[j] = __expf(v[j]-mx); s += v[j]; }
    }
    s = wsum64(s);
    float inv = 1.0f / s;
    #pragma unroll
    for (int j = 0; j < 4; j++){
      int i = l + 64*j;
      if (i < LW) ww[i] = v[j]*inv;
    }
  }
  __syncthreads();

  // ---- context = sum_l word_w[l]*word_mean[l]
  {
    int d = t & 127, r = t >> 7;  // r in 0..3
    float s = 0.f;
    for (int i = r; i < LW; i += 4) s += ww[i]*wm[i*DD + d];
    red[r*DD + d] = s;
  }
  __syncthreads();
  if (t < DD) cx[t] = red[t] + red[DD+t] + red[2*DD+t] + red[3*DD+t];
  __syncthreads();

  float2 c2 = *(float2*)&cx[2*l];
  float2 hacc = {0.f, 0.f};

  // ---- Pass 3: sim softmax -> attn weights -> hidden
  for (int wrd = wv; wrd < LW; wrd += 8){
    long long p0 = base + (long long)wrd * NS;
    float2 e[NS]; int ids[NS]; float si[NS];
    #pragma unroll
    for (int s = 0; s < NS; s++){
      int id = in32[(p0 + s) << f];
      ids[s] = id;
      float2 ev = *(const float2*)(emb + (long long)id*DD + 2*l);
      e[s] = ev;
      si[s] = ev.x*c2.x + ev.y*c2.y;
    }
    #pragma unroll
    for (int s = 0; s < NS; s++) si[s] = wsum64(si[s]);
    float mx = fmaxf(fmaxf(fmaxf(si[0],si[1]), fmaxf(si[2],si[3])), si[4]);
    float pw[NS]; float ssum = 0.f;
    #pragma unroll
    for (int s = 0; s < NS; s++){ pw[s] = __expf(si[s]-mx); ssum += pw[s]; }
    float inv = 1.0f / ssum;
    #pragma unroll
    for (int s = 0; s < NS; s++){
      float aw = (ids[s] == 0) ? 0.f : pw[s]*inv*lw;   // PAD -> 0 (after softmax)
      hacc.x += aw*e[s].x; hacc.y += aw*e[s].y;
    }
  }
  red[wv*DD + 2*l]     = hacc.x;
  red[wv*DD + 2*l + 1] = hacc.y;
  __syncthreads();
  if (t < DD){
    float h = 0.f;
    #pragma unroll
    for (int w = 0; w < 8; w++) h += red[w*DD + t];
    hiddenB[b*DD + t] = f2bf(h);
  }
}

// ---------------------------------------------------------------------------
// GEMM: logits = hidden(256x128) @ W(128x50000) + b_out, bf16 MFMA.
// Per block: 64-column stripe, all 256 rows (4 waves x 64 rows).
// Writes bf16 logits + per-(row,stripe) (max, sumexp) partials.
__global__ __launch_bounds__(256) void k_gemm(
    const unsigned short* __restrict__ Wt,   // [50000][128] bf16
    const unsigned short* __restrict__ hB,   // [256][128] bf16
    const float* __restrict__ b_out,
    unsigned short* __restrict__ logits,     // [256][50000] bf16
    float* __restrict__ stats)               // [256][NSTRIPES][2]
{
  __shared__ unsigned short Bs[64*128];      // [n][k] bf16, XOR-swizzled, 16 KB
  int blk = blockIdx.x;
  long long n0 = (long long)blk * 64;
  int t = threadIdx.x;

  // stage Wt stripe -> LDS (swizzled dest to kill ds_read bank conflicts)
  #pragma unroll
  for (int c = t; c < 1024; c += 256){
    int n = c >> 4;
    int bo = (c & 15) << 4;
    long long ng = n0 + n;
    uint4 v = {0u,0u,0u,0u};
    if (ng < OO) v = *(const uint4*)((const char*)Wt + ng*256 + bo);
    *(uint4*)((char*)Bs + n*256 + (bo ^ ((n & 7) << 4))) = v;
  }
  __syncthreads();

  int wv = t >> 6, l = t & 63;
  int lr = l & 15, lg = l >> 4;

  // A fragments: wave's 64 rows x full K=128, held in registers
  bf16x8 a[4][4];
  #pragma unroll
  for (int mt = 0; mt < 4; mt++)
    #pragma unroll
    for (int ks = 0; ks < 4; ks++){
      int m = wv*64 + mt*16 + lr;
      int k = ks*32 + lg*8;
      a[mt][ks] = *(const bf16x8*)(hB + m*DD + k);
    }

  f32x4 acc[4][4];
  #pragma unroll
  for (int mt = 0; mt < 4; mt++)
    #pragma unroll
    for (int nt = 0; nt < 4; nt++)
      acc[mt][nt] = (f32x4){0.f,0.f,0.f,0.f};

  #pragma unroll
  for (int nt = 0; nt < 4; nt++){
    #pragma unroll
    for (int ks = 0; ks < 4; ks++){
      int n = nt*16 + lr;
      int kb = (ks*32 + lg*8) * 2;
      bf16x8 bfr = *(const bf16x8*)((const char*)Bs + n*256 + (kb ^ ((n & 7) << 4)));
      #pragma unroll
      for (int mt = 0; mt < 4; mt++)
        acc[mt][nt] = __builtin_amdgcn_mfma_f32_16x16x32_bf16(a[mt][ks], bfr, acc[mt][nt], 0, 0, 0);
    }
  }

  // epilogue: + b_out, bf16 store, online (max, sumexp) per row
  float bv[4]; int nvalid[4]; long long ngl[4];
  #pragma unroll
  for (int nt = 0; nt < 4; nt++){
    long long ng = n0 + nt*16 + lr;
    ngl[nt] = ng;
    nvalid[nt] = (ng < OO);
    bv[nt] = nvalid[nt] ? b_out[ng] : 0.f;
  }
  #pragma unroll
  for (int mt = 0; mt < 4; mt++){
    #pragma unroll
    for (int j = 0; j < 4; j++){
      int m = wv*64 + mt*16 + lg*4 + j;   // C/D: col=lane&15, row=(lane>>4)*4+reg
      float v[4];
      #pragma unroll
      for (int nt = 0; nt < 4; nt++){
        float x = acc[mt][nt][j] + bv[nt];
        v[nt] = nvalid[nt] ? x : -INFINITY;
        if (nvalid[nt]) logits[(long long)m*OO + ngl[nt]] = f2bf(x);
      }
      float mx = fmaxf(fmaxf(v[0],v[1]), fmaxf(v[2],v[3]));
      #pragma unroll
      for (int o = 1; o < 16; o <<= 1) mx = fmaxf(mx, __shfl_xor(mx, o, 64));
      float s = 0.f;
      #pragma unroll
      for (int nt = 0; nt < 4; nt++) s += __expf(v[nt] - mx);
      #pragma unroll
      for (int o = 1; o < 16; o <<= 1) s += __shfl_xor(s, o, 64);
      if (lr == 0){
        stats[((long long)m*NSTRIPES + blk)*2 + 0] = mx;
        stats[((long long)m*NSTRIPES + blk)*2 + 1] = s;
      }
    }
  }
}

// ---------------------------------------------------------------------------
__global__ void k_reduce(const float* __restrict__ stats, float* __restrict__ Lrow){
  int m = blockIdx.x, l = threadIdx.x;  // 64 threads
  float mx = -INFINITY, s = 0.f;
  for (int i = l; i < NSTRIPES; i += 64){
    float mb = stats[((long long)m*NSTRIPES + i)*2 + 0];
    float sb = stats[((long long)m*NSTRIPES + i)*2 + 1];
    float nm = fmaxf(mx, mb);
    s = s*__expf(mx - nm) + sb*__expf(mb - nm);
    mx = nm;
  }
  #pragma unroll
  for (int o = 1; o < 64; o <<= 1){
    float mo = __shfl_xor(mx, o, 64);
    float so = __shfl_xor(s, o, 64);
    float nm = fmaxf(mx, mo);
    s = s*__expf(mx - nm) + so*__expf(mo - nm);
    mx = nm;
  }
  if (l == 0) Lrow[m] = mx + __logf(s);
}

// ---------------------------------------------------------------------------
// out[m][n] = bf2f(logits[m][n]) - L[m];  8 elems/thread, exact grid.
__global__ __launch_bounds__(256) void k_finalize(
    const unsigned short* __restrict__ logits,
    const float* __restrict__ Lrow, float* __restrict__ out)
{
  long long c = (long long)blockIdx.x*256 + threadIdx.x;  // 1,600,000 chunks
  int row = (int)(c / 6250);                              // 50000/8 per row
  float Lv = Lrow[row];
  u16x8 v = *(const u16x8*)(logits + c*8);
  float4 o0, o1;
  o0.x = bf2f(v[0]) - Lv; o0.y = bf2f(v[1]) - Lv;
  o0.z = bf2f(v[2]) - Lv; o0.w = bf2f(v[3]) - Lv;
  o1.x = bf2f(v[4]) - Lv; o1.y = bf2f(v[5]) - Lv;
  o1.z = bf2f(v[6]) - Lv; o1.w = bf2f(v[7]) - Lv;
  *(float4*)(out + c*8)     = o0;
  *(float4*)(out + c*8 + 4) = o1;
}

// ---------------------------------------------------------------------------
extern "C" void kernel_launch(void* const* d_in, const int* in_sizes, int n_in,
                              void* d_out, int out_size, void* d_ws, size_t ws_size,
                              hipStream_t stream)
{
  (void)in_sizes; (void)n_in; (void)out_size; (void)ws_size;
  const void* inputs          = d_in[0];
  const float* lw             = (const float*)d_in[1];
  const unsigned char* mask   = (const unsigned char*)d_in[2];
  const float* emb            = (const float*)d_in[3];
  const float* W              = (const float*)d_in[4];
  const float* bout           = (const float*)d_in[5];
  const float* w_attn         = (const float*)d_in[6];
  const float* b_attn         = (const float*)d_in[7];

  char* ws = (char*)d_ws;
  unsigned short* Wt     = (unsigned short*)(ws);               // 12,800,000 B
  unsigned short* hB     = (unsigned short*)(ws + 12800000);    //     65,536 B
  unsigned short* logits = (unsigned short*)(ws + 12865536);    // 25,600,000 B
  float* stats           = (float*)(ws + 38465536);             //  1,601,536 B
  float* Lrow            = (float*)(ws + 40067072);             //      1,024 B
  int*   flag            = (int*)(ws + 40068096);

  k_sniff<<<1, 64, 0, stream>>>((const unsigned*)inputs, flag);
  k_prepw<<<NSTRIPES, 256, 0, stream>>>(W, Wt);
  k_attn<<<MB, 512, 0, stream>>>((const int*)inputs, flag, lw, mask, emb,
                                 w_attn, b_attn, hB);
  k_gemm<<<NSTRIPES, 256, 0, stream>>>(Wt, hB, bout, logits, stats);
  k_reduce<<<MB, 64, 0, stream>>>(stats, Lrow);
  k_finalize<<<6250, 256, 0, stream>>>(logits, Lrow, (float*)d_out);
}

// Round 2
// 150.178 us; speedup vs baseline: 1.2166x; 1.2166x over previous
//
#include <hip/hip_runtime.h>
#include <hip/hip_bf16.h>
#include <stdint.h>

// Problem constants (from reference setup_inputs)
#define MB 256
#define LW 200      // words per batch
#define NS 5        // senses per word
#define DD 128      // embedding dim
#define OO 50000    // output vocab
#define LSTOK 1000  // LW*NS
#define WGRP 25     // word-groups per batch (8 words each)

#define NSTRIPES 782  // ceil(50000/64)

typedef __attribute__((ext_vector_type(8))) short bf16x8;
typedef __attribute__((ext_vector_type(4))) float f32x4;
typedef __attribute__((ext_vector_type(8))) unsigned short u16x8;

__device__ inline unsigned short f2bf(float f){
  unsigned u = __float_as_uint(f);
  unsigned r = (u + 0x7fffu + ((u >> 16) & 1u)) >> 16;  // RNE
  return (unsigned short)r;
}
__device__ inline float bf2f(unsigned short h){
  return __uint_as_float(((unsigned)h) << 16);
}
__device__ inline unsigned packbf(float a, float b){
  return (unsigned)f2bf(a) | ((unsigned)f2bf(b) << 16);
}
__device__ inline float wsum64(float v){
  #pragma unroll
  for (int o = 1; o < 64; o <<= 1) v += __shfl_xor(v, o, 64);
  return v;
}
__device__ inline float wmax64(float v){
  #pragma unroll
  for (int o = 1; o < 64; o <<= 1) v = fmaxf(v, __shfl_xor(v, o, 64));
  return v;
}

// ---------------------------------------------------------------------------
// Sniff whether inputs are int64 (odd dwords == high words == 0) or int32.
__global__ void k_sniff(const unsigned* __restrict__ p, int* __restrict__ flag){
  unsigned v = p[2*threadIdx.x + 1];
  unsigned long long b = __ballot(v != 0u);
  if (threadIdx.x == 0) *flag = (b == 0ull) ? 1 : 0;
}

// ---------------------------------------------------------------------------
// W (128 x 50000 f32, row-major) -> Wt (50000 x 128 bf16, row-major)
__global__ __launch_bounds__(256) void k_prepw(const float* __restrict__ W,
                                               unsigned short* __restrict__ Wt){
  __shared__ float tile[64][129];
  long long n0 = (long long)blockIdx.x * 64;
  int t = threadIdx.x;
  int j = t & 63, kk = t >> 6;
  #pragma unroll
  for (int k = kk; k < 128; k += 4){
    float v = 0.f;
    if (n0 + j < OO) v = W[(long long)k*OO + n0 + j];
    tile[j][k] = v;
  }
  __syncthreads();
  #pragma unroll
  for (int c = t; c < 4096; c += 256){
    int row = c >> 6, dw = c & 63;
    if (n0 + row < OO){
      unsigned pr = packbf(tile[row][2*dw], tile[row][2*dw+1]);
      ((unsigned*)Wt)[(n0 + row)*64 + dw] = pr;
    }
  }
}

// ---------------------------------------------------------------------------
// K1: gmean[b][d] = (sum over 1000 gathered rows) * lw * 0.2
__global__ __launch_bounds__(1024) void k_gmean(
    const int* __restrict__ in32, const int* __restrict__ flagp,
    const float* __restrict__ lwp, const float* __restrict__ emb,
    float* __restrict__ gmean)
{
  __shared__ float red[32*DD];   // 16 KB
  int b = blockIdx.x, t = threadIdx.x;
  int f = *flagp;
  long long base = (long long)b * LSTOK;
  int q = t & 31, r = t >> 5;    // q: float4 slot, r: 32 rows in flight
  float4 acc = {0.f,0.f,0.f,0.f};
  for (int i = r; i < LSTOK; i += 32){
    int idx = in32[(base + i) << f];
    float4 v = *(const float4*)(emb + (long long)idx*DD + q*4);
    acc.x += v.x; acc.y += v.y; acc.z += v.z; acc.w += v.w;
  }
  *(float4*)&red[r*DD + q*4] = acc;
  __syncthreads();
  if (t < DD){
    float s = 0.f;
    #pragma unroll
    for (int rr = 0; rr < 32; rr++) s += red[rr*DD + t];
    gmean[b*DD + t] = s * lwp[b] * 0.2f;
  }
}

// ---------------------------------------------------------------------------
// K2: per-word sense softmax -> word_mean (packed bf16) + word_imp.
// One wave per word; 8 words per block; grid = MB*WGRP = 6400 blocks.
__global__ __launch_bounds__(512) void k_sense(
    const int* __restrict__ in32, const int* __restrict__ flagp,
    const unsigned char* __restrict__ maskp, const float* __restrict__ emb,
    const float* __restrict__ gmean, const float* __restrict__ w_attn,
    const float* __restrict__ b_attn_p,
    unsigned* __restrict__ wmB,   // [MB*LW*64] packed bf16 pairs
    float* __restrict__ imp)      // [MB*LW]
{
  int blk = blockIdx.x, t = threadIdx.x;
  int b = blk / WGRP, g = blk % WGRP;
  int wv = t >> 6, l = t & 63;
  int wrd = g*8 + wv;
  int f = *flagp;
  long long p0 = (long long)b*LSTOK + (long long)wrd*NS;
  float2 g2 = *(const float2*)(gmean + b*DD + 2*l);

  float2 e[NS]; float si[NS];
  #pragma unroll
  for (int s = 0; s < NS; s++){
    int id = in32[(p0 + s) << f];
    float2 ev = *(const float2*)(emb + (long long)id*DD + 2*l);
    e[s] = ev;
    si[s] = ev.x*g2.x + ev.y*g2.y;
  }
  #pragma unroll
  for (int s = 0; s < NS; s++) si[s] = wsum64(si[s]);
  float mx = fmaxf(fmaxf(fmaxf(si[0],si[1]), fmaxf(si[2],si[3])), si[4]);
  float sw[NS]; float ssum = 0.f;
  #pragma unroll
  for (int s = 0; s < NS; s++){ sw[s] = __expf(si[s]-mx); ssum += sw[s]; }
  float inv = 1.0f / ssum;
  float2 m2 = {0.f, 0.f};
  #pragma unroll
  for (int s = 0; s < NS; s++){
    float w = sw[s]*inv;
    m2.x += w*e[s].x; m2.y += w*e[s].y;
  }
  wmB[((long long)b*LW + wrd)*64 + l] = packbf(m2.x, m2.y);
  float2 wa2 = *(const float2*)(w_attn + 2*l);
  float wi = wsum64(m2.x*wa2.x + m2.y*wa2.y) + *b_attn_p;
  if (maskp[(long long)b*LW + wrd]) wi = -INFINITY;
  if (l == 0) imp[(long long)b*LW + wrd] = wi;
}

// ---------------------------------------------------------------------------
// K3: word softmax over 200 -> context[b][128]
__global__ __launch_bounds__(512) void k_ctx(
    const float* __restrict__ imp, const unsigned* __restrict__ wmB,
    float* __restrict__ ctx)
{
  __shared__ float ww[LW];
  __shared__ float red[8*DD];
  int b = blockIdx.x, t = threadIdx.x;
  int wv = t >> 6, l = t & 63;
  if (wv == 0){
    float v[4]; float mx = -INFINITY;
    #pragma unroll
    for (int j = 0; j < 4; j++){
      int i = l + 64*j;
      v[j] = (i < LW) ? imp[(long long)b*LW + i] : -INFINITY;
      mx = fmaxf(mx, v[j]);
    }
    mx = wmax64(mx);
    float s = 0.f;
    #pragma unroll
    for (int j = 0; j < 4; j++){
      int i = l + 64*j;
      if (i < LW){ v[j] = __expf(v[j]-mx); s += v[j]; }
    }
    s = wsum64(s);
    float inv = 1.0f / s;
    #pragma unroll
    for (int j = 0; j < 4; j++){
      int i = l + 64*j;
      if (i < LW) ww[i] = v[j]*inv;
    }
  }
  __syncthreads();
  int r = t >> 6;                 // 0..7 row groups
  float s0 = 0.f, s1 = 0.f;
  for (int i = r; i < LW; i += 8){
    unsigned p = wmB[((long long)b*LW + i)*64 + l];
    float w = ww[i];
    s0 += w * bf2f((unsigned short)(p & 0xffffu));
    s1 += w * bf2f((unsigned short)(p >> 16));
  }
  red[r*DD + 2*l]   = s0;
  red[r*DD + 2*l+1] = s1;
  __syncthreads();
  if (t < DD){
    float s = 0.f;
    #pragma unroll
    for (int rr = 0; rr < 8; rr++) s += red[rr*DD + t];
    ctx[b*DD + t] = s;
  }
}

// ---------------------------------------------------------------------------
// K4: sim softmax -> attn weights -> per-block partial hidden.
// One wave per word; 8 words per block; grid = 6400 blocks.
__global__ __launch_bounds__(512) void k_hid(
    const int* __restrict__ in32, const int* __restrict__ flagp,
    const float* __restrict__ lwp, const float* __restrict__ emb,
    const float* __restrict__ ctx, float* __restrict__ hpart)
{
  __shared__ float red[8*DD];
  int blk = blockIdx.x, t = threadIdx.x;
  int b = blk / WGRP, g = blk % WGRP;
  int wv = t >> 6, l = t & 63;
  int wrd = g*8 + wv;
  int f = *flagp;
  float lw = lwp[b];
  long long p0 = (long long)b*LSTOK + (long long)wrd*NS;
  float2 c2 = *(const float2*)(ctx + b*DD + 2*l);

  float2 e[NS]; int ids[NS]; float si[NS];
  #pragma unroll
  for (int s = 0; s < NS; s++){
    int id = in32[(p0 + s) << f];
    ids[s] = id;
    float2 ev = *(const float2*)(emb + (long long)id*DD + 2*l);
    e[s] = ev;
    si[s] = ev.x*c2.x + ev.y*c2.y;
  }
  #pragma unroll
  for (int s = 0; s < NS; s++) si[s] = wsum64(si[s]);
  float mx = fmaxf(fmaxf(fmaxf(si[0],si[1]), fmaxf(si[2],si[3])), si[4]);
  float pw[NS]; float ssum = 0.f;
  #pragma unroll
  for (int s = 0; s < NS; s++){ pw[s] = __expf(si[s]-mx); ssum += pw[s]; }
  float inv = 1.0f / ssum;
  float2 hacc = {0.f, 0.f};
  #pragma unroll
  for (int s = 0; s < NS; s++){
    float aw = (ids[s] == 0) ? 0.f : pw[s]*inv*lw;
    hacc.x += aw*e[s].x; hacc.y += aw*e[s].y;
  }
  red[wv*DD + 2*l]   = hacc.x;
  red[wv*DD + 2*l+1] = hacc.y;
  __syncthreads();
  if (t < DD){
    float s = 0.f;
    #pragma unroll
    for (int w = 0; w < 8; w++) s += red[w*DD + t];
    hpart[((long long)b*WGRP + g)*DD + t] = s;
  }
}

// ---------------------------------------------------------------------------
// K5: hidden[b][d] = sum over 25 partials -> bf16
__global__ __launch_bounds__(128) void k_hred(
    const float* __restrict__ hpart, unsigned short* __restrict__ hB)
{
  int b = blockIdx.x, t = threadIdx.x;
  float s = 0.f;
  #pragma unroll
  for (int g = 0; g < WGRP; g++) s += hpart[((long long)b*WGRP + g)*DD + t];
  hB[b*DD + t] = f2bf(s);
}

// ---------------------------------------------------------------------------
// GEMM: logits = hidden(256x128) @ W(128x50000) + b_out, bf16 MFMA.
__global__ __launch_bounds__(256) void k_gemm(
    const unsigned short* __restrict__ Wt,   // [50000][128] bf16
    const unsigned short* __restrict__ hB,   // [256][128] bf16
    const float* __restrict__ b_out,
    unsigned short* __restrict__ logits,     // [256][50000] bf16
    float* __restrict__ stats)               // [256][NSTRIPES][2]
{
  __shared__ unsigned short Bs[64*128];      // [n][k] bf16, XOR-swizzled, 16 KB
  int blk = blockIdx.x;
  long long n0 = (long long)blk * 64;
  int t = threadIdx.x;

  #pragma unroll
  for (int c = t; c < 1024; c += 256){
    int n = c >> 4;
    int bo = (c & 15) << 4;
    long long ng = n0 + n;
    uint4 v = {0u,0u,0u,0u};
    if (ng < OO) v = *(const uint4*)((const char*)Wt + ng*256 + bo);
    *(uint4*)((char*)Bs + n*256 + (bo ^ ((n & 7) << 4))) = v;
  }
  __syncthreads();

  int wv = t >> 6, l = t & 63;
  int lr = l & 15, lg = l >> 4;

  bf16x8 a[4][4];
  #pragma unroll
  for (int mt = 0; mt < 4; mt++)
    #pragma unroll
    for (int ks = 0; ks < 4; ks++){
      int m = wv*64 + mt*16 + lr;
      int k = ks*32 + lg*8;
      a[mt][ks] = *(const bf16x8*)(hB + m*DD + k);
    }

  f32x4 acc[4][4];
  #pragma unroll
  for (int mt = 0; mt < 4; mt++)
    #pragma unroll
    for (int nt = 0; nt < 4; nt++)
      acc[mt][nt] = (f32x4){0.f,0.f,0.f,0.f};

  #pragma unroll
  for (int nt = 0; nt < 4; nt++){
    #pragma unroll
    for (int ks = 0; ks < 4; ks++){
      int n = nt*16 + lr;
      int kb = (ks*32 + lg*8) * 2;
      bf16x8 bfr = *(const bf16x8*)((const char*)Bs + n*256 + (kb ^ ((n & 7) << 4)));
      #pragma unroll
      for (int mt = 0; mt < 4; mt++)
        acc[mt][nt] = __builtin_amdgcn_mfma_f32_16x16x32_bf16(a[mt][ks], bfr, acc[mt][nt], 0, 0, 0);
    }
  }

  float bv[4]; int nvalid[4]; long long ngl[4];
  #pragma unroll
  for (int nt = 0; nt < 4; nt++){
    long long ng = n0 + nt*16 + lr;
    ngl[nt] = ng;
    nvalid[nt] = (ng < OO);
    bv[nt] = nvalid[nt] ? b_out[ng] : 0.f;
  }
  #pragma unroll
  for (int mt = 0; mt < 4; mt++){
    #pragma unroll
    for (int j = 0; j < 4; j++){
      int m = wv*64 + mt*16 + lg*4 + j;   // C/D: col=lane&15, row=(lane>>4)*4+reg
      float v[4];
      #pragma unroll
      for (int nt = 0; nt < 4; nt++){
        float x = acc[mt][nt][j] + bv[nt];
        v[nt] = nvalid[nt] ? x : -INFINITY;
        if (nvalid[nt]) logits[(long long)m*OO + ngl[nt]] = f2bf(x);
      }
      float mx = fmaxf(fmaxf(v[0],v[1]), fmaxf(v[2],v[3]));
      #pragma unroll
      for (int o = 1; o < 16; o <<= 1) mx = fmaxf(mx, __shfl_xor(mx, o, 64));
      float s = 0.f;
      #pragma unroll
      for (int nt = 0; nt < 4; nt++) s += __expf(v[nt] - mx);
      #pragma unroll
      for (int o = 1; o < 16; o <<= 1) s += __shfl_xor(s, o, 64);
      if (lr == 0){
        stats[((long long)m*NSTRIPES + blk)*2 + 0] = mx;
        stats[((long long)m*NSTRIPES + blk)*2 + 1] = s;
      }
    }
  }
}

// ---------------------------------------------------------------------------
__global__ void k_reduce(const float* __restrict__ stats, float* __restrict__ Lrow){
  int m = blockIdx.x, l = threadIdx.x;  // 64 threads
  float mx = -INFINITY, s = 0.f;
  for (int i = l; i < NSTRIPES; i += 64){
    float mb = stats[((long long)m*NSTRIPES + i)*2 + 0];
    float sb = stats[((long long)m*NSTRIPES + i)*2 + 1];
    float nm = fmaxf(mx, mb);
    s = s*__expf(mx - nm) + sb*__expf(mb - nm);
    mx = nm;
  }
  #pragma unroll
  for (int o = 1; o < 64; o <<= 1){
    float mo = __shfl_xor(mx, o, 64);
    float so = __shfl_xor(s, o, 64);
    float nm = fmaxf(mx, mo);
    s = s*__expf(mx - nm) + so*__expf(mo - nm);
    mx = nm;
  }
  if (l == 0) Lrow[m] = mx + __logf(s);
}

// ---------------------------------------------------------------------------
__global__ __launch_bounds__(256) void k_finalize(
    const unsigned short* __restrict__ logits,
    const float* __restrict__ Lrow, float* __restrict__ out)
{
  long long c = (long long)blockIdx.x*256 + threadIdx.x;  // 1,600,000 chunks
  int row = (int)(c / 6250);                              // 50000/8 per row
  float Lv = Lrow[row];
  u16x8 v = *(const u16x8*)(logits + c*8);
  float4 o0, o1;
  o0.x = bf2f(v[0]) - Lv; o0.y = bf2f(v[1]) - Lv;
  o0.z = bf2f(v[2]) - Lv; o0.w = bf2f(v[3]) - Lv;
  o1.x = bf2f(v[4]) - Lv; o1.y = bf2f(v[5]) - Lv;
  o1.z = bf2f(v[6]) - Lv; o1.w = bf2f(v[7]) - Lv;
  *(float4*)(out + c*8)     = o0;
  *(float4*)(out + c*8 + 4) = o1;
}

// ---------------------------------------------------------------------------
extern "C" void kernel_launch(void* const* d_in, const int* in_sizes, int n_in,
                              void* d_out, int out_size, void* d_ws, size_t ws_size,
                              hipStream_t stream)
{
  (void)in_sizes; (void)n_in; (void)out_size; (void)ws_size;
  const void* inputs          = d_in[0];
  const float* lw             = (const float*)d_in[1];
  const unsigned char* mask   = (const unsigned char*)d_in[2];
  const float* emb            = (const float*)d_in[3];
  const float* W              = (const float*)d_in[4];
  const float* bout           = (const float*)d_in[5];
  const float* w_attn         = (const float*)d_in[6];
  const float* b_attn         = (const float*)d_in[7];

  char* ws = (char*)d_ws;
  unsigned short* Wt     = (unsigned short*)(ws);               // 12,800,000 B
  unsigned short* hB     = (unsigned short*)(ws + 12800000);    //     65,536 B
  char* logregion        = ws + 12865536;                       // 25,600,000 B
  unsigned short* logits = (unsigned short*)logregion;
  // attention scratch aliased INSIDE the logits region (consumed before k_gemm)
  unsigned* wmB          = (unsigned*)(logregion);              // 13,107,200 B
  float* imp             = (float*)(logregion + 13107200);      //    204,800 B
  float* gmean           = (float*)(logregion + 13312000);      //    131,072 B
  float* ctx             = (float*)(logregion + 13443072);      //    131,072 B
  float* hpart           = (float*)(logregion + 13574144);      //  3,276,800 B
  float* stats           = (float*)(ws + 38465536);             //  1,601,536 B
  float* Lrow            = (float*)(ws + 40067072);             //      1,024 B
  int*   flag            = (int*)(ws + 40068096);

  const int* in32 = (const int*)inputs;

  k_sniff<<<1, 64, 0, stream>>>((const unsigned*)inputs, flag);
  k_prepw<<<NSTRIPES, 256, 0, stream>>>(W, Wt);
  k_gmean<<<MB, 1024, 0, stream>>>(in32, flag, lw, emb, gmean);
  k_sense<<<MB*WGRP, 512, 0, stream>>>(in32, flag, mask, emb, gmean,
                                       w_attn, b_attn, wmB, imp);
  k_ctx<<<MB, 512, 0, stream>>>(imp, wmB, ctx);
  k_hid<<<MB*WGRP, 512, 0, stream>>>(in32, flag, lw, emb, ctx, hpart);
  k_hred<<<MB, 128, 0, stream>>>(hpart, hB);
  k_gemm<<<NSTRIPES, 256, 0, stream>>>(Wt, hB, bout, logits, stats);
  k_reduce<<<MB, 64, 0, stream>>>(stats, Lrow);
  k_finalize<<<6250, 256, 0, stream>>>(logits, Lrow, (float*)d_out);
}